// Round 5
// baseline (205.610 us; speedup 1.0000x reference)
//
#include <hip/hip_runtime.h>

// LSTM tagger, hidden size 1. B=64, T=2048, E=256.
// Outputs: [0] sigmoid(mask(hs)) (B*T floats), [1] seq_length as floats (B).
//
// R5 structure:
//   xg_kernel: block=128 threads (2 waves), TILE=64 rows.
//     Stage: async global_load_lds width=16 — one instr = one contiguous 1 KiB
//       row -> LDS row stride 260 floats (1040 B, 16B-aligned; pad sits
//       between rows so the wave-uniform-base + lane*16 scatter is exact).
//     Compute: thread = row (64 rows/wave, each ds_read_b128 moves 1 KiB of
//       UNIQUE data); waves split the j-range (32 each). Weight index is made
//       wave-uniform via readfirstlane so weight reads scalarize to
//       s_load_dwordx4 (SMEM pipe, off the DS pipe). 2-way LDS reduction,
//       bias-fold + pre-scale (-log2e / +2log2e), time-major [t][b][4] store.
//   scan_kernel: 64 chunks x 32 output steps, 32-step warm-up from (0,0)
//     (chunk 0 exact; contraction E[log f] ~ -0.7/step -> error ~1e-10).

#define NLOG2E   (-1.4426950408889634f)
#define TWOLOG2E ( 2.8853900817779268f)

constexpr int Bb = 64;
constexpr int Tt = 2048;
constexpr int Ee = 256;
constexpr int TILE = 64;                 // rows per block
constexpr int STRW = 260;                // LDS row stride in floats (1040 B, 16B-aligned)

__global__ __launch_bounds__(128) void xg_kernel(
    const float* __restrict__ data, const float* __restrict__ w_ih,
    const float* __restrict__ b_ih, const float* __restrict__ b_hh,
    float* __restrict__ xg)
{
    __shared__ float lds[TILE * STRW + 2 * TILE * 4];   // data rows + reduction
    float4* red4 = (float4*)&lds[TILE * STRW];          // [wave][row] float4

    const int tid = threadIdx.x;
    const int l   = tid & 63;                                        // lane
    const int w   = __builtin_amdgcn_readfirstlane(tid >> 6);        // wave id (uniform)

    // ---- stage 64 rows (64 KiB), async direct-to-LDS, 32 rows per wave ----
    const size_t tilebase = (size_t)blockIdx.x * TILE * Ee;          // floats
    #pragma unroll
    for (int i = 0; i < 32; ++i) {
        const int r = w * 32 + i;
        __builtin_amdgcn_global_load_lds(
            (const __attribute__((address_space(1))) void*)(data + tilebase + (size_t)r * Ee + l * 4),
            (__attribute__((address_space(3))) void*)&lds[r * STRW],
            16, 0, 0);
    }
    __syncthreads();   // drains vmcnt (global_load_lds) + barrier

    // ---- compute: thread = row, wave w covers j in [32w, 32w+32) ----
    const float*  dr = &lds[l * STRW];
    const float4* wl = (const float4*)w_ih;             // wl[g*64 + j]

    float s0 = 0.f, s1 = 0.f, s2 = 0.f, s3 = 0.f;
    #pragma unroll 4
    for (int jj = 0; jj < 32; ++jj) {
        const int j = w * 32 + jj;                      // wave-uniform -> s_load weights
        const float4 d  = *(const float4*)(dr + 4 * j);
        const float4 w0 = wl[       j];
        const float4 w1 = wl[ 64 +  j];
        const float4 w2 = wl[128 +  j];
        const float4 w3 = wl[192 +  j];
        s0 = fmaf(d.w, w0.w, fmaf(d.z, w0.z, fmaf(d.y, w0.y, fmaf(d.x, w0.x, s0))));
        s1 = fmaf(d.w, w1.w, fmaf(d.z, w1.z, fmaf(d.y, w1.y, fmaf(d.x, w1.x, s1))));
        s2 = fmaf(d.w, w2.w, fmaf(d.z, w2.z, fmaf(d.y, w2.y, fmaf(d.x, w2.x, s2))));
        s3 = fmaf(d.w, w3.w, fmaf(d.z, w3.z, fmaf(d.y, w3.y, fmaf(d.x, w3.x, s3))));
    }

    float4 part; part.x = s0; part.y = s1; part.z = s2; part.w = s3;
    red4[w * TILE + l] = part;
    __syncthreads();

    if (w == 0) {
        const float4 a = red4[l];
        const float4 b2 = red4[TILE + l];
        const float g0 = a.x + b2.x + b_ih[0] + b_hh[0];
        const float g1 = a.y + b2.y + b_ih[1] + b_hh[1];
        const float g2 = a.z + b2.z + b_ih[2] + b_hh[2];
        const float g3 = a.w + b2.w + b_ih[3] + b_hh[3];
        float4 v;
        v.x = NLOG2E   * g0;   // i: sigmoid arg pre-scaled
        v.y = NLOG2E   * g1;   // f
        v.z = TWOLOG2E * g2;   // g: tanh arg pre-scaled
        v.w = NLOG2E   * g3;   // o
        const int row = blockIdx.x * TILE + l;   // tile never straddles a batch
        const int b   = row >> 11;               // row / T
        const int tg  = row & (Tt - 1);          // row % T
        ((float4*)xg)[tg * Bb + b] = v;          // time-major
    }
}

__device__ __forceinline__ float sig_from_scaled(float a) {
    // a = -log2e * x  ->  sigmoid(x) = 1 / (1 + 2^a)
    return __builtin_amdgcn_rcpf(1.0f + __builtin_amdgcn_exp2f(a));
}
__device__ __forceinline__ float tanh_from_scaled(float a) {
    // a = 2*log2e * x  ->  tanh(x) = 1 - 2/(1 + 2^a)
    return 1.0f - 2.0f * __builtin_amdgcn_rcpf(1.0f + __builtin_amdgcn_exp2f(a));
}

// chunk = blockIdx.x: 64 chunks x 32 output steps, warm-up 32 (chunk 0: 0).
__global__ __launch_bounds__(64) void scan_kernel(
    const float* __restrict__ xg, const float* __restrict__ w_hh,
    const int* __restrict__ seq_length, float* __restrict__ out)
{
    const int b = threadIdx.x;            // lane = batch
    const int chunk = blockIdx.x;
    const float wi = NLOG2E   * w_hh[0];
    const float wf = NLOG2E   * w_hh[1];
    const float wg = TWOLOG2E * w_hh[2];
    const float wo = NLOG2E   * w_hh[3];
    const int len = seq_length[b];

    const float4* x4   = (const float4*)xg;          // index t*64 + b
    float4*       orow = (float4*)(out + (size_t)b * Tt);

    const int warmG = (chunk == 0) ? 0 : 8;          // warm-up groups (x4 steps)
    const int g0    = chunk * 8 - warmG;             // first (global) group
    const int nG    = warmG + 8;                     // 8 or 16 groups

    float h = 0.0f, c = 0.0f;

    // depth-4 ring, one slot = 4 timesteps = 4 float4; static slot indices
    float4 r0[4], r1[4], r2[4], r3[4];
    #pragma unroll
    for (int i = 0; i < 4; ++i) {
        r0[i] = x4[((g0 + 0) * 4 + i) * Bb + b];
        r1[i] = x4[((g0 + 1) * 4 + i) * Bb + b];
        r2[i] = x4[((g0 + 2) * 4 + i) * Bb + b];
        r3[i] = x4[((g0 + 3) * 4 + i) * Bb + b];
    }

#define STEP(xv)                                                   \
    {                                                              \
        const float ai = fmaf(h, wi, (xv).x);                      \
        const float af = fmaf(h, wf, (xv).y);                      \
        const float ag = fmaf(h, wg, (xv).z);                      \
        const float ao = fmaf(h, wo, (xv).w);                      \
        const float i_ = sig_from_scaled(ai);                      \
        const float f_ = sig_from_scaled(af);                      \
        const float g_ = tanh_from_scaled(ag);                     \
        const float o_ = sig_from_scaled(ao);                      \
        c = fmaf(f_, c, i_ * g_);                                  \
        h = o_ * tanh_from_scaled(TWOLOG2E * c);                   \
    }
#define OUTV(t_) sig_from_scaled(NLOG2E * (((t_) < len) ? h : 0.0f))

#define BODY(j, slot)                                              \
    {                                                              \
        const int gg = g0 + (j);                                   \
        const int tt = gg * 4;                                     \
        float4 ov;                                                 \
        STEP(slot[0]); ov.x = OUTV(tt + 0);                        \
        STEP(slot[1]); ov.y = OUTV(tt + 1);                        \
        STEP(slot[2]); ov.z = OUTV(tt + 2);                        \
        STEP(slot[3]); ov.w = OUTV(tt + 3);                        \
        if ((j) >= warmG) orow[gg] = ov;                           \
        if ((j) + 4 < nG) {                                        \
            const int tp = (gg + 4) * 4;                           \
            slot[0] = x4[(tp + 0) * Bb + b];                       \
            slot[1] = x4[(tp + 1) * Bb + b];                       \
            slot[2] = x4[(tp + 2) * Bb + b];                       \
            slot[3] = x4[(tp + 3) * Bb + b];                       \
        }                                                          \
    }

    const int nM = nG >> 2;
    for (int m = 0; m < nM; ++m) {
        const int j = m * 4;
        BODY(j + 0, r0);
        BODY(j + 1, r1);
        BODY(j + 2, r2);
        BODY(j + 3, r3);
    }
#undef BODY
#undef STEP
#undef OUTV

    // Output 1: seq_length as float, appended after the B*T hs outputs.
    if (chunk == 0) out[(size_t)Bb * Tt + b] = (float)len;
}

extern "C" void kernel_launch(void* const* d_in, const int* in_sizes, int n_in,
                              void* d_out, int out_size, void* d_ws, size_t ws_size,
                              hipStream_t stream) {
    const float* data = (const float*)d_in[0];
    const int*   seq  = (const int*)  d_in[1];
    const float* w_ih = (const float*)d_in[2];
    const float* w_hh = (const float*)d_in[3];
    const float* b_ih = (const float*)d_in[4];
    const float* b_hh = (const float*)d_in[5];
    float* out = (float*)d_out;
    float* xg  = (float*)d_ws;   // B*T*4 floats = 2 MiB scratch

    xg_kernel<<<dim3(Bb * Tt / TILE), dim3(128), 0, stream>>>(data, w_ih, b_ih, b_hh, xg);
    scan_kernel<<<dim3(Tt / 32), dim3(64), 0, stream>>>(xg, w_hh, seq, out);
}

// Round 6
// 204.761 us; speedup vs baseline: 1.0041x; 1.0041x over previous
//
#include <hip/hip_runtime.h>

// LSTM tagger, hidden size 1. B=64, T=2048, E=256.
// Outputs: [0] sigmoid(mask(hs)) (B*T floats), [1] seq_length as floats (B).
//
// R6 structure:
//   xg_kernel: OCCUPANCY-FIRST. 1 wave per block, TILE=16 rows, LDS 16.25 KiB
//     -> ~9-10 independent barrier-groups per CU (R4/R5 had 2; their
//     stage-drain stalls had nothing to overlap with — both sat at ~50 us).
//     Stage: 16x async global_load_lds width=16, one contiguous 1 KiB row per
//       instr into LDS rows at stride 260 floats (pad between rows keeps the
//       wave-uniform-base + lane*16 scatter exact).
//     Compute: thread=(r=tid&15, jq=tid>>4); row stride 260 => bank group
//       (r+jj) mod 8 — uniform, no conflicts beyond the 8-cyc b128 floor.
//       Weights are 4-valued per wave-iter (L1-hot 4-line loads).
//     Reduce: 2 rounds of shfl_xor (16,32) — no LDS, no second barrier.
//     Gate args bias-folded + pre-scaled (-log2e / +2log2e), time-major
//     [t][b][4] store by lanes 0..15.
//   scan_kernel: unchanged — 64 chunks x 32 output steps, 32-step warm-up
//     from (0,0) (chunk 0 exact; contraction E[log f] ~ -0.7/step).

#define NLOG2E   (-1.4426950408889634f)
#define TWOLOG2E ( 2.8853900817779268f)

constexpr int Bb = 64;
constexpr int Tt = 2048;
constexpr int Ee = 256;
constexpr int TILE = 16;                 // rows per block
constexpr int STRW = 260;                // LDS row stride (floats); 1040 B, 16B-aligned

__global__ __launch_bounds__(64) void xg_kernel(
    const float* __restrict__ data, const float* __restrict__ w_ih,
    const float* __restrict__ b_ih, const float* __restrict__ b_hh,
    float* __restrict__ xg)
{
    __shared__ float lds[TILE * STRW];                  // 16.25 KiB

    const int tid = threadIdx.x;                        // 0..63

    // ---- stage 16 rows (16 KiB), async direct-to-LDS ----
    const size_t tilebase = (size_t)blockIdx.x * (TILE * Ee);
    #pragma unroll
    for (int r = 0; r < TILE; ++r) {
        __builtin_amdgcn_global_load_lds(
            (const __attribute__((address_space(1))) void*)(data + tilebase + r * Ee + tid * 4),
            (__attribute__((address_space(3))) void*)&lds[r * STRW],
            16, 0, 0);
    }
    __syncthreads();   // vmcnt(0) drain; barrier is trivial for a 1-wave block

    // ---- compute: thread = (row r, j-quarter jq); 16 b128 reads each ----
    const int r  = tid & 15;
    const int jq = tid >> 4;                            // 0..3
    const float*  dr = &lds[r * STRW];
    const float4* wl = (const float4*)w_ih;             // wl[g*64 + j]

    float s0 = 0.f, s1 = 0.f, s2 = 0.f, s3 = 0.f;
    #pragma unroll 4
    for (int jj = 0; jj < 16; ++jj) {
        const int j = jq * 16 + jj;
        const float4 d  = *(const float4*)(dr + 4 * j);
        const float4 w0 = wl[       j];
        const float4 w1 = wl[ 64 +  j];
        const float4 w2 = wl[128 +  j];
        const float4 w3 = wl[192 +  j];
        s0 = fmaf(d.w, w0.w, fmaf(d.z, w0.z, fmaf(d.y, w0.y, fmaf(d.x, w0.x, s0))));
        s1 = fmaf(d.w, w1.w, fmaf(d.z, w1.z, fmaf(d.y, w1.y, fmaf(d.x, w1.x, s1))));
        s2 = fmaf(d.w, w2.w, fmaf(d.z, w2.z, fmaf(d.y, w2.y, fmaf(d.x, w2.x, s2))));
        s3 = fmaf(d.w, w3.w, fmaf(d.z, w3.z, fmaf(d.y, w3.y, fmaf(d.x, w3.x, s3))));
    }

    // ---- reduce over jq: butterfly across lane bits 4,5 (no LDS) ----
    s0 += __shfl_xor(s0, 16, 64); s1 += __shfl_xor(s1, 16, 64);
    s2 += __shfl_xor(s2, 16, 64); s3 += __shfl_xor(s3, 16, 64);
    s0 += __shfl_xor(s0, 32, 64); s1 += __shfl_xor(s1, 32, 64);
    s2 += __shfl_xor(s2, 32, 64); s3 += __shfl_xor(s3, 32, 64);

    if (tid < 16) {
        float4 v;
        v.x = NLOG2E   * (s0 + b_ih[0] + b_hh[0]);   // i: sigmoid arg pre-scaled
        v.y = NLOG2E   * (s1 + b_ih[1] + b_hh[1]);   // f
        v.z = TWOLOG2E * (s2 + b_ih[2] + b_hh[2]);   // g: tanh arg pre-scaled
        v.w = NLOG2E   * (s3 + b_ih[3] + b_hh[3]);   // o
        const int row = blockIdx.x * TILE + r;       // tile never straddles a batch
        const int b   = row >> 11;                   // row / T
        const int tg  = row & (Tt - 1);              // row % T
        ((float4*)xg)[tg * Bb + b] = v;              // time-major
    }
}

__device__ __forceinline__ float sig_from_scaled(float a) {
    // a = -log2e * x  ->  sigmoid(x) = 1 / (1 + 2^a)
    return __builtin_amdgcn_rcpf(1.0f + __builtin_amdgcn_exp2f(a));
}
__device__ __forceinline__ float tanh_from_scaled(float a) {
    // a = 2*log2e * x  ->  tanh(x) = 1 - 2/(1 + 2^a)
    return 1.0f - 2.0f * __builtin_amdgcn_rcpf(1.0f + __builtin_amdgcn_exp2f(a));
}

// chunk = blockIdx.x: 64 chunks x 32 output steps, warm-up 32 (chunk 0: 0).
__global__ __launch_bounds__(64) void scan_kernel(
    const float* __restrict__ xg, const float* __restrict__ w_hh,
    const int* __restrict__ seq_length, float* __restrict__ out)
{
    const int b = threadIdx.x;            // lane = batch
    const int chunk = blockIdx.x;
    const float wi = NLOG2E   * w_hh[0];
    const float wf = NLOG2E   * w_hh[1];
    const float wg = TWOLOG2E * w_hh[2];
    const float wo = NLOG2E   * w_hh[3];
    const int len = seq_length[b];

    const float4* x4   = (const float4*)xg;          // index t*64 + b
    float4*       orow = (float4*)(out + (size_t)b * Tt);

    const int warmG = (chunk == 0) ? 0 : 8;          // warm-up groups (x4 steps)
    const int g0    = chunk * 8 - warmG;             // first (global) group
    const int nG    = warmG + 8;                     // 8 or 16 groups

    float h = 0.0f, c = 0.0f;

    // depth-4 ring, one slot = 4 timesteps = 4 float4; static slot indices
    float4 r0[4], r1[4], r2[4], r3[4];
    #pragma unroll
    for (int i = 0; i < 4; ++i) {
        r0[i] = x4[((g0 + 0) * 4 + i) * Bb + b];
        r1[i] = x4[((g0 + 1) * 4 + i) * Bb + b];
        r2[i] = x4[((g0 + 2) * 4 + i) * Bb + b];
        r3[i] = x4[((g0 + 3) * 4 + i) * Bb + b];
    }

#define STEP(xv)                                                   \
    {                                                              \
        const float ai = fmaf(h, wi, (xv).x);                      \
        const float af = fmaf(h, wf, (xv).y);                      \
        const float ag = fmaf(h, wg, (xv).z);                      \
        const float ao = fmaf(h, wo, (xv).w);                      \
        const float i_ = sig_from_scaled(ai);                      \
        const float f_ = sig_from_scaled(af);                      \
        const float g_ = tanh_from_scaled(ag);                     \
        const float o_ = sig_from_scaled(ao);                      \
        c = fmaf(f_, c, i_ * g_);                                  \
        h = o_ * tanh_from_scaled(TWOLOG2E * c);                   \
    }
#define OUTV(t_) sig_from_scaled(NLOG2E * (((t_) < len) ? h : 0.0f))

#define BODY(j, slot)                                              \
    {                                                              \
        const int gg = g0 + (j);                                   \
        const int tt = gg * 4;                                     \
        float4 ov;                                                 \
        STEP(slot[0]); ov.x = OUTV(tt + 0);                        \
        STEP(slot[1]); ov.y = OUTV(tt + 1);                        \
        STEP(slot[2]); ov.z = OUTV(tt + 2);                        \
        STEP(slot[3]); ov.w = OUTV(tt + 3);                        \
        if ((j) >= warmG) orow[gg] = ov;                           \
        if ((j) + 4 < nG) {                                        \
            const int tp = (gg + 4) * 4;                           \
            slot[0] = x4[(tp + 0) * Bb + b];                       \
            slot[1] = x4[(tp + 1) * Bb + b];                       \
            slot[2] = x4[(tp + 2) * Bb + b];                       \
            slot[3] = x4[(tp + 3) * Bb + b];                       \
        }                                                          \
    }

    const int nM = nG >> 2;
    for (int m = 0; m < nM; ++m) {
        const int j = m * 4;
        BODY(j + 0, r0);
        BODY(j + 1, r1);
        BODY(j + 2, r2);
        BODY(j + 3, r3);
    }
#undef BODY
#undef STEP
#undef OUTV

    // Output 1: seq_length as float, appended after the B*T hs outputs.
    if (chunk == 0) out[(size_t)Bb * Tt + b] = (float)len;
}

extern "C" void kernel_launch(void* const* d_in, const int* in_sizes, int n_in,
                              void* d_out, int out_size, void* d_ws, size_t ws_size,
                              hipStream_t stream) {
    const float* data = (const float*)d_in[0];
    const int*   seq  = (const int*)  d_in[1];
    const float* w_ih = (const float*)d_in[2];
    const float* w_hh = (const float*)d_in[3];
    const float* b_ih = (const float*)d_in[4];
    const float* b_hh = (const float*)d_in[5];
    float* out = (float*)d_out;
    float* xg  = (float*)d_ws;   // B*T*4 floats = 2 MiB scratch

    xg_kernel<<<dim3(Bb * Tt / TILE), dim3(64), 0, stream>>>(data, w_ih, b_ih, b_hh, xg);
    scan_kernel<<<dim3(Tt / 32), dim3(64), 0, stream>>>(xg, w_hh, seq, out);
}

// Round 7
// 196.478 us; speedup vs baseline: 1.0465x; 1.0422x over previous
//
#include <hip/hip_runtime.h>

// LSTM tagger, hidden size 1. B=64, T=2048, E=256.
// Outputs: [0] sigmoid(mask(hs)) (B*T floats), [1] seq_length as floats (B).
//
// R7: SKIP MASKED WORK. out[b,t] = sigmoid(0) = 0.5 for t >= len[b], and h
//   never flows backward — so xg tiles with t0 >= len[b] are unobservable.
//   xg_kernel early-exits those tiles WITHOUT reading data (halves the
//   dominant 128 MiB read in expectation; E[len] ~ T/2). Skipped xg stays
//   harness-poisoned (0xAA = -3e-13, finite); the scan selects (t<len ? h : 0)
//   BEFORE the sigmoid, so garbage h only reaches masked outputs. Warm-up for
//   any chunk with a live output (len > 32k) reads only t < 32k < len, which
//   is always computed — live outputs stay exact.
//
//   xg_kernel (R6 core): 1 wave/block, TILE=16 rows, grid (T/16, B).
//     Stage: 16x async global_load_lds width=16 (contiguous 1 KiB row/instr,
//     LDS row stride 260 floats). Compute: thread=(r,jq), b128 LDS reads,
//     L1-hot 4-line weight loads. Reduce: 2x shfl_xor. Bias-fold + pre-scale
//     (-log2e / +2log2e), time-major [t][b][4] store.
//   scan_kernel: 64 chunks x 32 output steps, 32-step warm-up from (0,0)
//     (chunk 0 exact; contraction E[log f] ~ -0.7/step -> error ~1e-10).

#define NLOG2E   (-1.4426950408889634f)
#define TWOLOG2E ( 2.8853900817779268f)

constexpr int Bb = 64;
constexpr int Tt = 2048;
constexpr int Ee = 256;
constexpr int TILE = 16;                 // rows per block
constexpr int STRW = 260;                // LDS row stride (floats); 1040 B, 16B-aligned

__global__ __launch_bounds__(64) void xg_kernel(
    const float* __restrict__ data, const float* __restrict__ w_ih,
    const float* __restrict__ b_ih, const float* __restrict__ b_hh,
    const int* __restrict__ seq_length, float* __restrict__ xg)
{
    __shared__ float lds[TILE * STRW];                  // 16.25 KiB

    const int by = blockIdx.y;                          // batch
    const int t0 = blockIdx.x * TILE;                   // first timestep of tile
    if (t0 >= seq_length[by]) return;                   // unobservable tile: skip read

    const int tid = threadIdx.x;                        // 0..63

    // ---- stage 16 rows (16 KiB), async direct-to-LDS ----
    const size_t tilebase = ((size_t)by * Tt + t0) * Ee;
    #pragma unroll
    for (int r = 0; r < TILE; ++r) {
        __builtin_amdgcn_global_load_lds(
            (const __attribute__((address_space(1))) void*)(data + tilebase + r * Ee + tid * 4),
            (__attribute__((address_space(3))) void*)&lds[r * STRW],
            16, 0, 0);
    }
    __syncthreads();   // vmcnt(0) drain; barrier trivial for a 1-wave block

    // ---- compute: thread = (row r, j-quarter jq); 16 b128 reads each ----
    const int r  = tid & 15;
    const int jq = tid >> 4;                            // 0..3
    const float*  dr = &lds[r * STRW];
    const float4* wl = (const float4*)w_ih;             // wl[g*64 + j]

    float s0 = 0.f, s1 = 0.f, s2 = 0.f, s3 = 0.f;
    #pragma unroll 4
    for (int jj = 0; jj < 16; ++jj) {
        const int j = jq * 16 + jj;
        const float4 d  = *(const float4*)(dr + 4 * j);
        const float4 w0 = wl[       j];
        const float4 w1 = wl[ 64 +  j];
        const float4 w2 = wl[128 +  j];
        const float4 w3 = wl[192 +  j];
        s0 = fmaf(d.w, w0.w, fmaf(d.z, w0.z, fmaf(d.y, w0.y, fmaf(d.x, w0.x, s0))));
        s1 = fmaf(d.w, w1.w, fmaf(d.z, w1.z, fmaf(d.y, w1.y, fmaf(d.x, w1.x, s1))));
        s2 = fmaf(d.w, w2.w, fmaf(d.z, w2.z, fmaf(d.y, w2.y, fmaf(d.x, w2.x, s2))));
        s3 = fmaf(d.w, w3.w, fmaf(d.z, w3.z, fmaf(d.y, w3.y, fmaf(d.x, w3.x, s3))));
    }

    // ---- reduce over jq: butterfly across lane bits 4,5 (no LDS) ----
    s0 += __shfl_xor(s0, 16, 64); s1 += __shfl_xor(s1, 16, 64);
    s2 += __shfl_xor(s2, 16, 64); s3 += __shfl_xor(s3, 16, 64);
    s0 += __shfl_xor(s0, 32, 64); s1 += __shfl_xor(s1, 32, 64);
    s2 += __shfl_xor(s2, 32, 64); s3 += __shfl_xor(s3, 32, 64);

    if (tid < 16) {
        float4 v;
        v.x = NLOG2E   * (s0 + b_ih[0] + b_hh[0]);   // i: sigmoid arg pre-scaled
        v.y = NLOG2E   * (s1 + b_ih[1] + b_hh[1]);   // f
        v.z = TWOLOG2E * (s2 + b_ih[2] + b_hh[2]);   // g: tanh arg pre-scaled
        v.w = NLOG2E   * (s3 + b_ih[3] + b_hh[3]);   // o
        ((float4*)xg)[(t0 + r) * Bb + by] = v;       // time-major
    }
}

__device__ __forceinline__ float sig_from_scaled(float a) {
    // a = -log2e * x  ->  sigmoid(x) = 1 / (1 + 2^a)
    return __builtin_amdgcn_rcpf(1.0f + __builtin_amdgcn_exp2f(a));
}
__device__ __forceinline__ float tanh_from_scaled(float a) {
    // a = 2*log2e * x  ->  tanh(x) = 1 - 2/(1 + 2^a)
    return 1.0f - 2.0f * __builtin_amdgcn_rcpf(1.0f + __builtin_amdgcn_exp2f(a));
}

// chunk = blockIdx.x: 64 chunks x 32 output steps, warm-up 32 (chunk 0: 0).
__global__ __launch_bounds__(64) void scan_kernel(
    const float* __restrict__ xg, const float* __restrict__ w_hh,
    const int* __restrict__ seq_length, float* __restrict__ out)
{
    const int b = threadIdx.x;            // lane = batch
    const int chunk = blockIdx.x;
    const float wi = NLOG2E   * w_hh[0];
    const float wf = NLOG2E   * w_hh[1];
    const float wg = TWOLOG2E * w_hh[2];
    const float wo = NLOG2E   * w_hh[3];
    const int len = seq_length[b];

    const float4* x4   = (const float4*)xg;          // index t*64 + b
    float4*       orow = (float4*)(out + (size_t)b * Tt);

    const int warmG = (chunk == 0) ? 0 : 8;          // warm-up groups (x4 steps)
    const int g0    = chunk * 8 - warmG;             // first (global) group
    const int nG    = warmG + 8;                     // 8 or 16 groups

    float h = 0.0f, c = 0.0f;

    // depth-4 ring, one slot = 4 timesteps = 4 float4; static slot indices
    float4 r0[4], r1[4], r2[4], r3[4];
    #pragma unroll
    for (int i = 0; i < 4; ++i) {
        r0[i] = x4[((g0 + 0) * 4 + i) * Bb + b];
        r1[i] = x4[((g0 + 1) * 4 + i) * Bb + b];
        r2[i] = x4[((g0 + 2) * 4 + i) * Bb + b];
        r3[i] = x4[((g0 + 3) * 4 + i) * Bb + b];
    }

#define STEP(xv)                                                   \
    {                                                              \
        const float ai = fmaf(h, wi, (xv).x);                      \
        const float af = fmaf(h, wf, (xv).y);                      \
        const float ag = fmaf(h, wg, (xv).z);                      \
        const float ao = fmaf(h, wo, (xv).w);                      \
        const float i_ = sig_from_scaled(ai);                      \
        const float f_ = sig_from_scaled(af);                      \
        const float g_ = tanh_from_scaled(ag);                     \
        const float o_ = sig_from_scaled(ao);                      \
        c = fmaf(f_, c, i_ * g_);                                  \
        h = o_ * tanh_from_scaled(TWOLOG2E * c);                   \
    }
#define OUTV(t_) sig_from_scaled(NLOG2E * (((t_) < len) ? h : 0.0f))

#define BODY(j, slot)                                              \
    {                                                              \
        const int gg = g0 + (j);                                   \
        const int tt = gg * 4;                                     \
        float4 ov;                                                 \
        STEP(slot[0]); ov.x = OUTV(tt + 0);                        \
        STEP(slot[1]); ov.y = OUTV(tt + 1);                        \
        STEP(slot[2]); ov.z = OUTV(tt + 2);                        \
        STEP(slot[3]); ov.w = OUTV(tt + 3);                        \
        if ((j) >= warmG) orow[gg] = ov;                           \
        if ((j) + 4 < nG) {                                        \
            const int tp = (gg + 4) * 4;                           \
            slot[0] = x4[(tp + 0) * Bb + b];                       \
            slot[1] = x4[(tp + 1) * Bb + b];                       \
            slot[2] = x4[(tp + 2) * Bb + b];                       \
            slot[3] = x4[(tp + 3) * Bb + b];                       \
        }                                                          \
    }

    const int nM = nG >> 2;
    for (int m = 0; m < nM; ++m) {
        const int j = m * 4;
        BODY(j + 0, r0);
        BODY(j + 1, r1);
        BODY(j + 2, r2);
        BODY(j + 3, r3);
    }
#undef BODY
#undef STEP
#undef OUTV

    // Output 1: seq_length as float, appended after the B*T hs outputs.
    if (chunk == 0) out[(size_t)Bb * Tt + b] = (float)len;
}

extern "C" void kernel_launch(void* const* d_in, const int* in_sizes, int n_in,
                              void* d_out, int out_size, void* d_ws, size_t ws_size,
                              hipStream_t stream) {
    const float* data = (const float*)d_in[0];
    const int*   seq  = (const int*)  d_in[1];
    const float* w_ih = (const float*)d_in[2];
    const float* w_hh = (const float*)d_in[3];
    const float* b_ih = (const float*)d_in[4];
    const float* b_hh = (const float*)d_in[5];
    float* out = (float*)d_out;
    float* xg  = (float*)d_ws;   // B*T*4 floats = 2 MiB scratch

    xg_kernel<<<dim3(Tt / TILE, Bb), dim3(64), 0, stream>>>(data, w_ih, b_ih, b_hh, seq, xg);
    scan_kernel<<<dim3(Tt / 32), dim3(64), 0, stream>>>(xg, w_hh, seq, out);
}